// Round 12
// baseline (267.031 us; speedup 1.0000x reference)
//
#include <hip/hip_runtime.h>

#define DIM 128
#define SLOTS 64

typedef __attribute__((ext_vector_type(8))) short bf16x8;
typedef __attribute__((ext_vector_type(4))) float f32x4;
typedef unsigned short u16;
typedef unsigned int u32;
typedef unsigned long long u64;

__device__ __forceinline__ float bf2f(u32 u) {
    return __builtin_bit_cast(float, u << 16);
}
__device__ __forceinline__ u16 f2bf(float f) {
    u32 u = __builtin_bit_cast(u32, f);
    u = (u + 0x7FFFu + ((u >> 16) & 1u)) >> 16;   // RNE
    return (u16)u;
}
__device__ __forceinline__ u32 pack2bf(float a, float b) {
    return (u32)f2bf(a) | ((u32)f2bf(b) << 16);
}

// ---------------- fused setup: deg/fill atomics (4 edges/thread) + bucket scatter + x->bf16 + Wt x3 ----------------
// bucket lo32 = (c << 8) | et  -> byte offset into xb is (lo & 0xFFFFFF00), type is (lo & 3)

__global__ __launch_bounds__(256) void k_setup(const int* __restrict__ row, const int* __restrict__ col,
                                               const int* __restrict__ et, const float* __restrict__ ew,
                                               int E, int* __restrict__ deg, int* __restrict__ fill,
                                               u64* __restrict__ ep,
                                               const float* __restrict__ x, u16* __restrict__ xb, int nx4,
                                               const float* __restrict__ W1, const float* __restrict__ W2,
                                               const float* __restrict__ W3,
                                               u16* __restrict__ Wt1, u16* __restrict__ Wt2,
                                               u16* __restrict__ Wt3, int nEb, int nXb) {
    int b = blockIdx.x, tid = threadIdx.x;
    if (b < nEb) {
        int e0 = (b * 256 + tid) * 4;
        #pragma unroll
        for (int i = 0; i < 4; i++) {
            int e = e0 + i;
            if (e < E) {
                int r = row[e], c = col[e];
                atomicAdd(&deg[c], 1);                    // in-degree (col counts)
                int pos = atomicAdd(&fill[r], 1);         // bucket slot for row
                if (pos < SLOTS)
                    ep[(size_t)r * SLOTS + pos] =
                        ((u64)__builtin_bit_cast(u32, ew[e]) << 32) | (u32)((c << 8) | et[e]);
            }
        }
    } else if (b < nEb + nXb) {
        int i = (b - nEb) * 256 + tid;
        if (i < nx4) {
            float4 v = ((const float4*)x)[i];
            ushort4 o;
            o.x = f2bf(v.x); o.y = f2bf(v.y); o.z = f2bf(v.z); o.w = f2bf(v.w);
            ((ushort4*)xb)[i] = o;
        }
    } else {
        int b2 = b - nEb - nXb;                    // 0..767
        const float* W = b2 < 256 ? W1 : (b2 < 512 ? W2 : W3);
        u16* Wt = b2 < 256 ? Wt1 : (b2 < 512 ? Wt2 : Wt3);
        int o = (b2 & 255) * 256 + tid;            // 0..65535
        // natural fragment order: o = chunk*1024 + col*8 + s, k = chunk*8 + s = t*128 + i
        int chunk = o >> 10;
        int c = (o >> 3) & 127;
        int k = chunk * 8 + (o & 7);
        Wt[o] = f2bf(W[(k >> 7) * 16384 + (k & 127) * 128 + c]);
    }
}

// ---------------- k_norm: fold full norm (rsqrt inline) into bucket weights + zero-pad to x8 ----------------

__global__ __launch_bounds__(256) void k_norm(const int* __restrict__ fill,
                                              const int* __restrict__ deg,
                                              u64* __restrict__ ep, int N) {
    int wid = threadIdx.x >> 6, lane = threadIdx.x & 63;
    int n = blockIdx.x * 4 + wid;
    if (n >= N) return;
    int cnt = fill[n]; if (cnt > SLOTS) cnt = SLOTS;
    int padded = (cnt + 7) & ~7;
    int dgn = deg[n];
    float dn = dgn > 0 ? rsqrtf((float)dgn) : 0.f;
    u64* eb = ep + (size_t)n * SLOTS;
    if (lane < cnt) {
        u64 q = eb[lane];
        u32 lo = (u32)q;
        int dgc = deg[lo >> 8];
        float dc = dgc > 0 ? rsqrtf((float)dgc) : 0.f;
        float wgt = __builtin_bit_cast(float, (u32)(q >> 32)) * dn * dc;
        eb[lane] = ((u64)__builtin_bit_cast(u32, wgt) << 32) | lo;
    } else if (lane < padded) {
        eb[lane] = 0;   // zero weight, col 0, type 0
    }
}

// ---------------- fused layer: 2-deep software-pipelined scalarized gather -> LDS -> MFMA ----------------
// block = 1024 thr / 16 waves = 16 nodes, one node per wave.
// Per iteration: decode S_k (vmcnt keeps G_{k-1} in flight because bucket k was issued
// BEFORE G_{k-1}) -> load bucket k+1 -> issue gathers G_k -> consume G_{k-1}.
// No copies of pending-load registers (ping-pong via 2x-unrolled loop).

template <int MODE>
__global__ __launch_bounds__(1024, 2) void k_layer(const u16* __restrict__ src,
                                                   const int* __restrict__ fill,
                                                   const u64* __restrict__ ep,
                                                   const u16* __restrict__ Wt,
                                                   const float* __restrict__ bias,
                                                   const float* __restrict__ x0,
                                                   const u16* __restrict__ z1b,
                                                   const u16* __restrict__ z2b,
                                                   float* __restrict__ outf,
                                                   u16* __restrict__ outb, int N) {
    __shared__ u16 sA[16 * 512];   // 16 KB
    int tid = threadIdx.x, wid = tid >> 6, lane = tid & 63;
    int n0 = blockIdx.x * 16;
    int n = n0 + wid;

    float2 a0 = {0.f, 0.f}, a1 = {0.f, 0.f}, a2 = {0.f, 0.f}, a3 = {0.f, 0.f};
    int cnt = 0;
    if (n < N) {
        cnt = fill[n];
        if (cnt > SLOTS) cnt = SLOTS;
    }
    const uint4* ebv = (const uint4*)(ep + (size_t)n * SLOTS);
    const char* xbase = (const char*)src + lane * 4;

#define RFL(x) __builtin_amdgcn_readfirstlane((int)(x))
#define LOADB(Bx, r_) { const uint4* p_ = ebv + (r_) * 4; \
        Bx[0] = p_[0]; Bx[1] = p_[1]; Bx[2] = p_[2]; Bx[3] = p_[3]; }
#define DEC(LO, WU, Bx) { \
        LO[0] = (u32)RFL(Bx[0].x); WU[0] = (u32)RFL(Bx[0].y); \
        LO[1] = (u32)RFL(Bx[0].z); WU[1] = (u32)RFL(Bx[0].w); \
        LO[2] = (u32)RFL(Bx[1].x); WU[2] = (u32)RFL(Bx[1].y); \
        LO[3] = (u32)RFL(Bx[1].z); WU[3] = (u32)RFL(Bx[1].w); \
        LO[4] = (u32)RFL(Bx[2].x); WU[4] = (u32)RFL(Bx[2].y); \
        LO[5] = (u32)RFL(Bx[2].z); WU[5] = (u32)RFL(Bx[2].w); \
        LO[6] = (u32)RFL(Bx[3].x); WU[6] = (u32)RFL(Bx[3].y); \
        LO[7] = (u32)RFL(Bx[3].z); WU[7] = (u32)RFL(Bx[3].w); }
#define ISSUE(G, LO) { \
        _Pragma("unroll") \
        for (int i_ = 0; i_ < 8; i_++) \
            G[i_] = *(const u32*)(xbase + (LO[i_] & 0xFFFFFF00u)); }
#define CONS(G, LO, WU) { \
        _Pragma("unroll") \
        for (int i_ = 0; i_ < 8; i_++) { \
            float w_  = __builtin_bit_cast(float, WU[i_]); \
            float vl_ = __builtin_bit_cast(float, G[i_] << 16); \
            float vh_ = __builtin_bit_cast(float, G[i_] & 0xFFFF0000u); \
            u32 t_ = LO[i_] & 3u; \
            float w0_ = t_ == 0u ? w_ : 0.f; \
            float w1_ = t_ == 1u ? w_ : 0.f; \
            float w2_ = t_ == 2u ? w_ : 0.f; \
            float w3_ = t_ == 3u ? w_ : 0.f; \
            a0.x = fmaf(vl_, w0_, a0.x); a0.y = fmaf(vh_, w0_, a0.y); \
            a1.x = fmaf(vl_, w1_, a1.x); a1.y = fmaf(vh_, w1_, a1.y); \
            a2.x = fmaf(vl_, w2_, a2.x); a2.y = fmaf(vh_, w2_, a2.y); \
            a3.x = fmaf(vl_, w3_, a3.x); a3.y = fmaf(vh_, w3_, a3.y); } }

    int rounds = (cnt + 7) >> 3;   // <= 8
    if (rounds > 0) {
        uint4 B0[4], B1[4];
        u32 S0lo[8], S0wu[8], S1lo[8], S1wu[8];
        u32 G0[8], G1[8];

        LOADB(B0, 0);
        DEC(S0lo, S0wu, B0);
        LOADB(B1, 1);             // safe overread within the 64-slot row
        ISSUE(G0, S0lo);

        int k = 1;
        for (; k + 1 < rounds; k += 2) {
            DEC(S1lo, S1wu, B1);          // waits bucket k, keeps G0 in flight
            LOADB(B0, k + 1);
            ISSUE(G1, S1lo);
            CONS(G0, S0lo, S0wu);
            DEC(S0lo, S0wu, B0);          // waits bucket k+1, keeps G1 in flight
            LOADB(B1, k + 2);             // safe overread
            ISSUE(G0, S0lo);
            CONS(G1, S1lo, S1wu);
        }
        if (k < rounds) {
            DEC(S1lo, S1wu, B1);
            ISSUE(G1, S1lo);
            CONS(G0, S0lo, S0wu);
            CONS(G1, S1lo, S1wu);
        } else {
            CONS(G0, S0lo, S0wu);
        }
    }
#undef CONS
#undef ISSUE
#undef DEC
#undef LOADB
#undef RFL

    // LDS store: row = wid (node), k = t*128 + 2*lane; swizzle byte ^= (row&7)<<4
    {
        u32 X = (u32)((wid & 7) << 4);
        char* base = (char*)sA + wid * 1024;
        *(u32*)(base + ((lane * 4 + 0  ) ^ X)) = pack2bf(a0.x, a0.y);
        *(u32*)(base + ((lane * 4 + 256) ^ X)) = pack2bf(a1.x, a1.y);
        *(u32*)(base + ((lane * 4 + 512) ^ X)) = pack2bf(a2.x, a2.y);
        *(u32*)(base + ((lane * 4 + 768) ^ X)) = pack2bf(a3.x, a3.y);
    }
    __syncthreads();

    // MFMA: [16,512] @ [512,128]; waves 0..7 -> col tile wid*16
    if (wid < 8) {
        int lr = lane & 15, lk = lane >> 4;
        u32 X = (u32)((lr & 7) << 4);
        const char* ab = (const char*)sA + lr * 1024;
        const u16* bb = Wt + lk * 1024 + (wid * 16 + lr) * 8;
        f32x4 acc = {};
        #pragma unroll
        for (int ks = 0; ks < 16; ks++) {
            bf16x8 af = *(const bf16x8*)(ab + ((ks * 64 + lk * 16) ^ X));
            bf16x8 bfv = *(const bf16x8*)(bb + ks * 4096);
            acc = __builtin_amdgcn_mfma_f32_16x16x32_bf16(af, bfv, acc, 0, 0, 0);
        }

        // epilogue: col = lane&15 (+tile), row = (lane>>4)*4 + r
        int colg = wid * 16 + lr;
        float bv = bias[colg];
        #pragma unroll
        for (int r = 0; r < 4; r++) {
            int nn = n0 + lk * 4 + r;
            if (nn < N) {
                size_t idx = (size_t)nn * DIM + colg;
                float v = acc[r] + bv;
                v = v > 0.f ? v : 0.01f * v;
                if (MODE == 1)
                    outf[idx] = 0.25f * (x0[idx] + bf2f(z1b[idx]) + bf2f(z2b[idx]) + v);
                else
                    outb[idx] = f2bf(v);
            }
        }
    }
}

// ---------------- launch ----------------

extern "C" void kernel_launch(void* const* d_in, const int* in_sizes, int n_in,
                              void* d_out, int out_size, void* d_ws, size_t ws_size,
                              hipStream_t stream) {
    const float* x     = (const float*)d_in[0];
    const int*   eidx  = (const int*)d_in[1];
    const int*   etype = (const int*)d_in[2];
    const float* eattr = (const float*)d_in[3];
    const float* W1 = (const float*)d_in[4];
    const float* b1 = (const float*)d_in[5];
    const float* W2 = (const float*)d_in[6];
    const float* b2 = (const float*)d_in[7];
    const float* W3 = (const float*)d_in[8];
    const float* b3 = (const float*)d_in[9];

    const int E = in_sizes[2];
    const int N = in_sizes[0] / DIM;
    const int* row = eidx;
    const int* col = eidx + E;

    char* w = (char*)d_ws;
    size_t off = 0;
    auto alloc = [&](size_t bytes) { size_t o = off; off = (off + bytes + 255) & ~255ULL; return o; };
    size_t deg_off = alloc((size_t)N * 4);
    int*   deg  = (int*)(w + deg_off);
    int*   fill = (int*)(w + alloc((size_t)N * 4));
    size_t zero_bytes = off - deg_off;
    u64*   ep   = (u64*)(w + alloc((size_t)N * SLOTS * 8));
    u16*   xb   = (u16*)(w + alloc((size_t)N * DIM * 2));
    u16*   z1b  = (u16*)(w + alloc((size_t)N * DIM * 2));
    u16*   z2b  = (u16*)(w + alloc((size_t)N * DIM * 2));
    u16*   Wt1  = (u16*)(w + alloc(65536 * 2));
    u16*   Wt2  = (u16*)(w + alloc(65536 * 2));
    u16*   Wt3  = (u16*)(w + alloc(65536 * 2));

    hipMemsetAsync(deg, 0, zero_bytes, stream);

    int nx4 = N * DIM / 4;
    int nEb = (E + 1023) / 1024;    // 4 edges per thread
    int nXb = (nx4 + 255) / 256;

    k_setup<<<nEb + nXb + 768, 256, 0, stream>>>(row, col, etype, eattr, E, deg, fill, ep,
                                                 x, xb, nx4, W1, W2, W3, Wt1, Wt2, Wt3, nEb, nXb);
    k_norm<<<(N + 3) / 4, 256, 0, stream>>>(fill, deg, ep, N);

    int grid = (N + 15) / 16;
    k_layer<0><<<grid, 1024, 0, stream>>>(xb,  fill, ep, Wt1, b1, nullptr, nullptr, nullptr, nullptr, z1b, N);
    k_layer<0><<<grid, 1024, 0, stream>>>(z1b, fill, ep, Wt2, b2, nullptr, nullptr, nullptr, nullptr, z2b, N);
    k_layer<1><<<grid, 1024, 0, stream>>>(z2b, fill, ep, Wt3, b3, x, z1b, z2b, (float*)d_out, nullptr, N);
}

// Round 13
// 237.883 us; speedup vs baseline: 1.1225x; 1.1225x over previous
//
#include <hip/hip_runtime.h>

#define DIM 128
#define SLOTS 64

typedef __attribute__((ext_vector_type(8))) short bf16x8;
typedef __attribute__((ext_vector_type(4))) float f32x4;
typedef __attribute__((ext_vector_type(2))) float f32x2;
typedef unsigned short u16;
typedef unsigned int u32;
typedef unsigned long long u64;

__device__ __forceinline__ float bf2f(u32 u) {
    return __builtin_bit_cast(float, u << 16);
}
__device__ __forceinline__ u16 f2bf(float f) {
    u32 u = __builtin_bit_cast(u32, f);
    u = (u + 0x7FFFu + ((u >> 16) & 1u)) >> 16;   // RNE
    return (u16)u;
}
__device__ __forceinline__ u32 pack2bf(float a, float b) {
    return (u32)f2bf(a) | ((u32)f2bf(b) << 16);
}

// ---------------- fused setup: deg/fill atomics (8 edges/thread) + bucket scatter + x->bf16 + Wt x3 ----------------
// bucket lo32 = (c << 8) | et  -> byte offset into xb is (lo & 0xFFFFFF00), type is (lo & 3)

__global__ __launch_bounds__(256) void k_setup(const int* __restrict__ row, const int* __restrict__ col,
                                               const int* __restrict__ et, const float* __restrict__ ew,
                                               int E, int* __restrict__ deg, int* __restrict__ fill,
                                               u64* __restrict__ ep,
                                               const float* __restrict__ x, u16* __restrict__ xb, int nx4,
                                               const float* __restrict__ W1, const float* __restrict__ W2,
                                               const float* __restrict__ W3,
                                               u16* __restrict__ Wt1, u16* __restrict__ Wt2,
                                               u16* __restrict__ Wt3, int nEb, int nXb) {
    int b = blockIdx.x, tid = threadIdx.x;
    if (b < nEb) {
        int e0 = (b * 256 + tid) * 8;
        #pragma unroll
        for (int i = 0; i < 8; i++) {
            int e = e0 + i;
            if (e < E) {
                int r = row[e], c = col[e];
                atomicAdd(&deg[c], 1);                    // in-degree (col counts)
                int pos = atomicAdd(&fill[r], 1);         // bucket slot for row
                if (pos < SLOTS)
                    ep[(size_t)r * SLOTS + pos] =
                        ((u64)__builtin_bit_cast(u32, ew[e]) << 32) | (u32)((c << 8) | et[e]);
            }
        }
    } else if (b < nEb + nXb) {
        int i = (b - nEb) * 256 + tid;
        if (i < nx4) {
            float4 v = ((const float4*)x)[i];
            ushort4 o;
            o.x = f2bf(v.x); o.y = f2bf(v.y); o.z = f2bf(v.z); o.w = f2bf(v.w);
            ((ushort4*)xb)[i] = o;
        }
    } else {
        int b2 = b - nEb - nXb;                    // 0..767
        const float* W = b2 < 256 ? W1 : (b2 < 512 ? W2 : W3);
        u16* Wt = b2 < 256 ? Wt1 : (b2 < 512 ? Wt2 : Wt3);
        int o = (b2 & 255) * 256 + tid;            // 0..65535
        // natural fragment order: o = chunk*1024 + col*8 + s, k = chunk*8 + s = t*128 + i
        int chunk = o >> 10;
        int c = (o >> 3) & 127;
        int k = chunk * 8 + (o & 7);
        Wt[o] = f2bf(W[(k >> 7) * 16384 + (k & 127) * 128 + c]);
    }
}

// ---------------- k_norm: fold full norm (rsqrt inline) into bucket weights + zero-pad to x8 ----------------

__global__ __launch_bounds__(256) void k_norm(const int* __restrict__ fill,
                                              const int* __restrict__ deg,
                                              u64* __restrict__ ep, int N) {
    int wid = threadIdx.x >> 6, lane = threadIdx.x & 63;
    int n = blockIdx.x * 4 + wid;
    if (n >= N) return;
    int cnt = fill[n]; if (cnt > SLOTS) cnt = SLOTS;
    int padded = (cnt + 7) & ~7;
    int dgn = deg[n];
    float dn = dgn > 0 ? rsqrtf((float)dgn) : 0.f;
    u64* eb = ep + (size_t)n * SLOTS;
    if (lane < cnt) {
        u64 q = eb[lane];
        u32 lo = (u32)q;
        int dgc = deg[lo >> 8];
        float dc = dgc > 0 ? rsqrtf((float)dgc) : 0.f;
        float wgt = __builtin_bit_cast(float, (u32)(q >> 32)) * dn * dc;
        eb[lane] = ((u64)__builtin_bit_cast(u32, wgt) << 32) | lo;
    } else if (lane < padded) {
        eb[lane] = 0;   // zero weight, col 0, type 0
    }
}

// ---------------- fused layer: scalarized gather + PACKED fp32 accumulate -> LDS -> MFMA ----------------
// block = 1024 thr / 16 waves = 16 nodes, one node per wave (R11 structure, pipeline reverted).
// Decode on SALU via readfirstlane; accumulate via v_pk_fma_f32 (f32x2 elementwise fma):
// ~6 VALU/edge instead of ~12 -> VALU floor halves.

template <int MODE>
__global__ __launch_bounds__(1024, 2) void k_layer(const u16* __restrict__ src,
                                                   const int* __restrict__ fill,
                                                   const u64* __restrict__ ep,
                                                   const u16* __restrict__ Wt,
                                                   const float* __restrict__ bias,
                                                   const float* __restrict__ x0,
                                                   const u16* __restrict__ z1b,
                                                   const u16* __restrict__ z2b,
                                                   float* __restrict__ outf,
                                                   u16* __restrict__ outb, int N) {
    __shared__ u16 sA[16 * 512];   // 16 KB
    int tid = threadIdx.x, wid = tid >> 6, lane = tid & 63;
    int n0 = blockIdx.x * 16;
    int n = n0 + wid;

    f32x2 a0 = {0.f, 0.f}, a1 = {0.f, 0.f}, a2 = {0.f, 0.f}, a3 = {0.f, 0.f};
    int cnt = 0;
    if (n < N) {
        cnt = fill[n];
        if (cnt > SLOTS) cnt = SLOTS;
    }
    const u64* eb = ep + (size_t)n * SLOTS;
    const char* xbase = (const char*)src + lane * 4;

#define RFL(x) __builtin_amdgcn_readfirstlane((int)(x))

#define EDGE(lo_, wu_, v_) { \
        float w_  = __builtin_bit_cast(float, (u32)(wu_)); \
        f32x2 vv_; \
        vv_[0] = __builtin_bit_cast(float, (v_) << 16); \
        vv_[1] = __builtin_bit_cast(float, (v_) & 0xFFFF0000u); \
        u32 t_ = (u32)(lo_) & 3u; \
        float w0_ = t_ == 0u ? w_ : 0.f; \
        float w1_ = t_ == 1u ? w_ : 0.f; \
        float w2_ = t_ == 2u ? w_ : 0.f; \
        float w3_ = t_ == 3u ? w_ : 0.f; \
        a0 = __builtin_elementwise_fma(vv_, (f32x2){w0_, w0_}, a0); \
        a1 = __builtin_elementwise_fma(vv_, (f32x2){w1_, w1_}, a1); \
        a2 = __builtin_elementwise_fma(vv_, (f32x2){w2_, w2_}, a2); \
        a3 = __builtin_elementwise_fma(vv_, (f32x2){w3_, w3_}, a3); }

    // buckets zero-padded to multiple of 8 -> unmasked rounds; bucket data scalarized
    for (int j = 0; j < cnt; j += 8) {
        const uint4* ebv = (const uint4*)(eb + j);
        uint4 qa = ebv[0], qb = ebv[1], qc = ebv[2], qd = ebv[3];
        u32 lo0 = (u32)RFL(qa.x), wu0 = (u32)RFL(qa.y);
        u32 lo1 = (u32)RFL(qa.z), wu1 = (u32)RFL(qa.w);
        u32 lo2 = (u32)RFL(qb.x), wu2 = (u32)RFL(qb.y);
        u32 lo3 = (u32)RFL(qb.z), wu3 = (u32)RFL(qb.w);
        u32 lo4 = (u32)RFL(qc.x), wu4 = (u32)RFL(qc.y);
        u32 lo5 = (u32)RFL(qc.z), wu5 = (u32)RFL(qc.w);
        u32 lo6 = (u32)RFL(qd.x), wu6 = (u32)RFL(qd.y);
        u32 lo7 = (u32)RFL(qd.z), wu7 = (u32)RFL(qd.w);
        u32 v0 = *(const u32*)(xbase + (lo0 & 0xFFFFFF00u));
        u32 v1 = *(const u32*)(xbase + (lo1 & 0xFFFFFF00u));
        u32 v2 = *(const u32*)(xbase + (lo2 & 0xFFFFFF00u));
        u32 v3 = *(const u32*)(xbase + (lo3 & 0xFFFFFF00u));
        u32 v4 = *(const u32*)(xbase + (lo4 & 0xFFFFFF00u));
        u32 v5 = *(const u32*)(xbase + (lo5 & 0xFFFFFF00u));
        u32 v6 = *(const u32*)(xbase + (lo6 & 0xFFFFFF00u));
        u32 v7 = *(const u32*)(xbase + (lo7 & 0xFFFFFF00u));
        EDGE(lo0, wu0, v0); EDGE(lo1, wu1, v1);
        EDGE(lo2, wu2, v2); EDGE(lo3, wu3, v3);
        EDGE(lo4, wu4, v4); EDGE(lo5, wu5, v5);
        EDGE(lo6, wu6, v6); EDGE(lo7, wu7, v7);
    }
#undef EDGE
#undef RFL

    // LDS store: row = wid (node), k = t*128 + 2*lane; swizzle byte ^= (row&7)<<4
    {
        u32 X = (u32)((wid & 7) << 4);
        char* base = (char*)sA + wid * 1024;
        *(u32*)(base + ((lane * 4 + 0  ) ^ X)) = pack2bf(a0[0], a0[1]);
        *(u32*)(base + ((lane * 4 + 256) ^ X)) = pack2bf(a1[0], a1[1]);
        *(u32*)(base + ((lane * 4 + 512) ^ X)) = pack2bf(a2[0], a2[1]);
        *(u32*)(base + ((lane * 4 + 768) ^ X)) = pack2bf(a3[0], a3[1]);
    }
    __syncthreads();

    // MFMA: [16,512] @ [512,128]; waves 0..7 -> col tile wid*16
    if (wid < 8) {
        int lr = lane & 15, lk = lane >> 4;
        u32 X = (u32)((lr & 7) << 4);
        const char* ab = (const char*)sA + lr * 1024;
        const u16* bb = Wt + lk * 1024 + (wid * 16 + lr) * 8;
        f32x4 acc = {};
        #pragma unroll
        for (int ks = 0; ks < 16; ks++) {
            bf16x8 af = *(const bf16x8*)(ab + ((ks * 64 + lk * 16) ^ X));
            bf16x8 bfv = *(const bf16x8*)(bb + ks * 4096);
            acc = __builtin_amdgcn_mfma_f32_16x16x32_bf16(af, bfv, acc, 0, 0, 0);
        }

        // epilogue: col = lane&15 (+tile), row = (lane>>4)*4 + r
        int colg = wid * 16 + lr;
        float bv = bias[colg];
        #pragma unroll
        for (int r = 0; r < 4; r++) {
            int nn = n0 + lk * 4 + r;
            if (nn < N) {
                size_t idx = (size_t)nn * DIM + colg;
                float v = acc[r] + bv;
                v = v > 0.f ? v : 0.01f * v;
                if (MODE == 1)
                    outf[idx] = 0.25f * (x0[idx] + bf2f(z1b[idx]) + bf2f(z2b[idx]) + v);
                else
                    outb[idx] = f2bf(v);
            }
        }
    }
}

// ---------------- launch ----------------

extern "C" void kernel_launch(void* const* d_in, const int* in_sizes, int n_in,
                              void* d_out, int out_size, void* d_ws, size_t ws_size,
                              hipStream_t stream) {
    const float* x     = (const float*)d_in[0];
    const int*   eidx  = (const int*)d_in[1];
    const int*   etype = (const int*)d_in[2];
    const float* eattr = (const float*)d_in[3];
    const float* W1 = (const float*)d_in[4];
    const float* b1 = (const float*)d_in[5];
    const float* W2 = (const float*)d_in[6];
    const float* b2 = (const float*)d_in[7];
    const float* W3 = (const float*)d_in[8];
    const float* b3 = (const float*)d_in[9];

    const int E = in_sizes[2];
    const int N = in_sizes[0] / DIM;
    const int* row = eidx;
    const int* col = eidx + E;

    char* w = (char*)d_ws;
    size_t off = 0;
    auto alloc = [&](size_t bytes) { size_t o = off; off = (off + bytes + 255) & ~255ULL; return o; };
    size_t deg_off = alloc((size_t)N * 4);
    int*   deg  = (int*)(w + deg_off);
    int*   fill = (int*)(w + alloc((size_t)N * 4));
    size_t zero_bytes = off - deg_off;
    u64*   ep   = (u64*)(w + alloc((size_t)N * SLOTS * 8));
    u16*   xb   = (u16*)(w + alloc((size_t)N * DIM * 2));
    u16*   z1b  = (u16*)(w + alloc((size_t)N * DIM * 2));
    u16*   z2b  = (u16*)(w + alloc((size_t)N * DIM * 2));
    u16*   Wt1  = (u16*)(w + alloc(65536 * 2));
    u16*   Wt2  = (u16*)(w + alloc(65536 * 2));
    u16*   Wt3  = (u16*)(w + alloc(65536 * 2));

    hipMemsetAsync(deg, 0, zero_bytes, stream);

    int nx4 = N * DIM / 4;
    int nEb = (E + 2047) / 2048;    // 8 edges per thread
    int nXb = (nx4 + 255) / 256;

    k_setup<<<nEb + nXb + 768, 256, 0, stream>>>(row, col, etype, eattr, E, deg, fill, ep,
                                                 x, xb, nx4, W1, W2, W3, Wt1, Wt2, Wt3, nEb, nXb);
    k_norm<<<(N + 3) / 4, 256, 0, stream>>>(fill, deg, ep, N);

    int grid = (N + 15) / 16;
    k_layer<0><<<grid, 1024, 0, stream>>>(xb,  fill, ep, Wt1, b1, nullptr, nullptr, nullptr, nullptr, z1b, N);
    k_layer<0><<<grid, 1024, 0, stream>>>(z1b, fill, ep, Wt2, b2, nullptr, nullptr, nullptr, nullptr, z2b, N);
    k_layer<1><<<grid, 1024, 0, stream>>>(z2b, fill, ep, Wt3, b3, x, z1b, z2b, (float*)d_out, nullptr, N);
}

// Round 14
// 230.007 us; speedup vs baseline: 1.1610x; 1.0342x over previous
//
#include <hip/hip_runtime.h>

#define DIM 128
#define SLOTS 64

typedef __attribute__((ext_vector_type(8))) short bf16x8;
typedef __attribute__((ext_vector_type(4))) float f32x4;
typedef __attribute__((ext_vector_type(2))) float f32x2;
typedef unsigned short u16;
typedef unsigned int u32;
typedef unsigned long long u64;

__device__ __forceinline__ float bf2f(u32 u) {
    return __builtin_bit_cast(float, u << 16);
}
__device__ __forceinline__ u16 f2bf(float f) {
    u32 u = __builtin_bit_cast(u32, f);
    u = (u + 0x7FFFu + ((u >> 16) & 1u)) >> 16;   // RNE
    return (u16)u;
}
__device__ __forceinline__ u32 pack2bf(float a, float b) {
    return (u32)f2bf(a) | ((u32)f2bf(b) << 16);
}

// ---------------- fused setup: deg/fill atomics (4 edges/thread) + bucket scatter + x->bf16 + Wt x3 ----------------
// bucket lo32 = (c << 8) | et  -> byte offset into xb is (lo & 0xFFFFFF00), type is (lo & 3)

__global__ __launch_bounds__(256) void k_setup(const int* __restrict__ row, const int* __restrict__ col,
                                               const int* __restrict__ et, const float* __restrict__ ew,
                                               int E, int* __restrict__ deg, int* __restrict__ fill,
                                               u64* __restrict__ ep,
                                               const float* __restrict__ x, u16* __restrict__ xb, int nx4,
                                               const float* __restrict__ W1, const float* __restrict__ W2,
                                               const float* __restrict__ W3,
                                               u16* __restrict__ Wt1, u16* __restrict__ Wt2,
                                               u16* __restrict__ Wt3, int nEb, int nXb) {
    int b = blockIdx.x, tid = threadIdx.x;
    if (b < nEb) {
        int e0 = (b * 256 + tid) * 4;
        #pragma unroll
        for (int i = 0; i < 4; i++) {
            int e = e0 + i;
            if (e < E) {
                int r = row[e], c = col[e];
                atomicAdd(&deg[c], 1);                    // in-degree (col counts)
                int pos = atomicAdd(&fill[r], 1);         // bucket slot for row
                if (pos < SLOTS)
                    ep[(size_t)r * SLOTS + pos] =
                        ((u64)__builtin_bit_cast(u32, ew[e]) << 32) | (u32)((c << 8) | et[e]);
            }
        }
    } else if (b < nEb + nXb) {
        int i = (b - nEb) * 256 + tid;
        if (i < nx4) {
            float4 v = ((const float4*)x)[i];
            ushort4 o;
            o.x = f2bf(v.x); o.y = f2bf(v.y); o.z = f2bf(v.z); o.w = f2bf(v.w);
            ((ushort4*)xb)[i] = o;
        }
    } else {
        int b2 = b - nEb - nXb;                    // 0..767
        const float* W = b2 < 256 ? W1 : (b2 < 512 ? W2 : W3);
        u16* Wt = b2 < 256 ? Wt1 : (b2 < 512 ? Wt2 : Wt3);
        int o = (b2 & 255) * 256 + tid;            // 0..65535
        // natural fragment order: o = chunk*1024 + col*8 + s, k = chunk*8 + s = t*128 + i
        int chunk = o >> 10;
        int c = (o >> 3) & 127;
        int k = chunk * 8 + (o & 7);
        Wt[o] = f2bf(W[(k >> 7) * 16384 + (k & 127) * 128 + c]);
    }
}

// ---------------- k_norm: fold full norm (rsqrt inline) into bucket weights + zero-pad to x8 ----------------

__global__ __launch_bounds__(256) void k_norm(const int* __restrict__ fill,
                                              const int* __restrict__ deg,
                                              u64* __restrict__ ep, int N) {
    int wid = threadIdx.x >> 6, lane = threadIdx.x & 63;
    int n = blockIdx.x * 4 + wid;
    if (n >= N) return;
    int cnt = fill[n]; if (cnt > SLOTS) cnt = SLOTS;
    int padded = (cnt + 7) & ~7;
    int dgn = deg[n];
    float dn = dgn > 0 ? rsqrtf((float)dgn) : 0.f;
    u64* eb = ep + (size_t)n * SLOTS;
    if (lane < cnt) {
        u64 q = eb[lane];
        u32 lo = (u32)q;
        int dgc = deg[lo >> 8];
        float dc = dgc > 0 ? rsqrtf((float)dgc) : 0.f;
        float wgt = __builtin_bit_cast(float, (u32)(q >> 32)) * dn * dc;
        eb[lane] = ((u64)__builtin_bit_cast(u32, wgt) << 32) | lo;
    } else if (lane < padded) {
        eb[lane] = 0;   // zero weight, col 0, type 0
    }
}

// ---------------- fused layer: register-resident bucket (readlane decode) -> gather -> LDS -> MFMA ----------------
// block = 1024 thr / 16 waves = 16 nodes, one node per wave.
// ONE coalesced load eb[lane] pulls the whole 512B bucket into 2 VGPRs; every edge is then
// decoded via v_readlane (uniform index) -> the address stream is register-resident, so
// gathers across ALL rounds can be in flight simultaneously (no bucket-load chain).

template <int MODE>
__global__ __launch_bounds__(1024, 2) void k_layer(const u16* __restrict__ src,
                                                   const int* __restrict__ fill,
                                                   const u64* __restrict__ ep,
                                                   const u16* __restrict__ Wt,
                                                   const float* __restrict__ bias,
                                                   const float* __restrict__ x0,
                                                   const u16* __restrict__ z1b,
                                                   const u16* __restrict__ z2b,
                                                   float* __restrict__ outf,
                                                   u16* __restrict__ outb, int N) {
    __shared__ u16 sA[16 * 512];   // 16 KB
    int tid = threadIdx.x, wid = tid >> 6, lane = tid & 63;
    int n0 = blockIdx.x * 16;
    int n = n0 + wid;

    f32x2 a0 = {0.f, 0.f}, a1 = {0.f, 0.f}, a2 = {0.f, 0.f}, a3 = {0.f, 0.f};
    int cnt = 0;
    if (n < N) {
        cnt = fill[n];
        if (cnt > SLOTS) cnt = SLOTS;
    }
    // whole bucket in registers: lane l holds slot l
    u64 myq = ep[(size_t)n * SLOTS + lane];
    u32 mylo = (u32)myq;
    u32 mywu = (u32)(myq >> 32);
    const char* xbase = (const char*)src + lane * 4;

#define RL(x, i_) ((u32)__builtin_amdgcn_readlane((int)(x), (i_)))

#define EDGE(lo_, wu_, v_) { \
        float w_  = __builtin_bit_cast(float, (u32)(wu_)); \
        f32x2 vv_; \
        vv_[0] = __builtin_bit_cast(float, (v_) << 16); \
        vv_[1] = __builtin_bit_cast(float, (v_) & 0xFFFF0000u); \
        u32 t_ = (u32)(lo_) & 3u; \
        float w0_ = t_ == 0u ? w_ : 0.f; \
        float w1_ = t_ == 1u ? w_ : 0.f; \
        float w2_ = t_ == 2u ? w_ : 0.f; \
        float w3_ = t_ == 3u ? w_ : 0.f; \
        a0 = __builtin_elementwise_fma(vv_, (f32x2){w0_, w0_}, a0); \
        a1 = __builtin_elementwise_fma(vv_, (f32x2){w1_, w1_}, a1); \
        a2 = __builtin_elementwise_fma(vv_, (f32x2){w2_, w2_}, a2); \
        a3 = __builtin_elementwise_fma(vv_, (f32x2){w3_, w3_}, a3); }

    // buckets zero-padded to multiple of 8 -> unmasked rounds; decode entirely from registers
    for (int j = 0; j < cnt; j += 8) {
        u32 lo0 = RL(mylo, j + 0), wu0 = RL(mywu, j + 0);
        u32 lo1 = RL(mylo, j + 1), wu1 = RL(mywu, j + 1);
        u32 lo2 = RL(mylo, j + 2), wu2 = RL(mywu, j + 2);
        u32 lo3 = RL(mylo, j + 3), wu3 = RL(mywu, j + 3);
        u32 lo4 = RL(mylo, j + 4), wu4 = RL(mywu, j + 4);
        u32 lo5 = RL(mylo, j + 5), wu5 = RL(mywu, j + 5);
        u32 lo6 = RL(mylo, j + 6), wu6 = RL(mywu, j + 6);
        u32 lo7 = RL(mylo, j + 7), wu7 = RL(mywu, j + 7);
        u32 v0 = *(const u32*)(xbase + (lo0 & 0xFFFFFF00u));
        u32 v1 = *(const u32*)(xbase + (lo1 & 0xFFFFFF00u));
        u32 v2 = *(const u32*)(xbase + (lo2 & 0xFFFFFF00u));
        u32 v3 = *(const u32*)(xbase + (lo3 & 0xFFFFFF00u));
        u32 v4 = *(const u32*)(xbase + (lo4 & 0xFFFFFF00u));
        u32 v5 = *(const u32*)(xbase + (lo5 & 0xFFFFFF00u));
        u32 v6 = *(const u32*)(xbase + (lo6 & 0xFFFFFF00u));
        u32 v7 = *(const u32*)(xbase + (lo7 & 0xFFFFFF00u));
        EDGE(lo0, wu0, v0); EDGE(lo1, wu1, v1);
        EDGE(lo2, wu2, v2); EDGE(lo3, wu3, v3);
        EDGE(lo4, wu4, v4); EDGE(lo5, wu5, v5);
        EDGE(lo6, wu6, v6); EDGE(lo7, wu7, v7);
    }
#undef EDGE
#undef RL

    // LDS store: row = wid (node), k = t*128 + 2*lane; swizzle byte ^= (row&7)<<4
    {
        u32 X = (u32)((wid & 7) << 4);
        char* base = (char*)sA + wid * 1024;
        *(u32*)(base + ((lane * 4 + 0  ) ^ X)) = pack2bf(a0[0], a0[1]);
        *(u32*)(base + ((lane * 4 + 256) ^ X)) = pack2bf(a1[0], a1[1]);
        *(u32*)(base + ((lane * 4 + 512) ^ X)) = pack2bf(a2[0], a2[1]);
        *(u32*)(base + ((lane * 4 + 768) ^ X)) = pack2bf(a3[0], a3[1]);
    }
    __syncthreads();

    // MFMA: [16,512] @ [512,128]; waves 0..7 -> col tile wid*16
    if (wid < 8) {
        int lr = lane & 15, lk = lane >> 4;
        u32 X = (u32)((lr & 7) << 4);
        const char* ab = (const char*)sA + lr * 1024;
        const u16* bb = Wt + lk * 1024 + (wid * 16 + lr) * 8;
        f32x4 acc = {};
        #pragma unroll
        for (int ks = 0; ks < 16; ks++) {
            bf16x8 af = *(const bf16x8*)(ab + ((ks * 64 + lk * 16) ^ X));
            bf16x8 bfv = *(const bf16x8*)(bb + ks * 4096);
            acc = __builtin_amdgcn_mfma_f32_16x16x32_bf16(af, bfv, acc, 0, 0, 0);
        }

        // epilogue: col = lane&15 (+tile), row = (lane>>4)*4 + r
        int colg = wid * 16 + lr;
        float bv = bias[colg];
        #pragma unroll
        for (int r = 0; r < 4; r++) {
            int nn = n0 + lk * 4 + r;
            if (nn < N) {
                size_t idx = (size_t)nn * DIM + colg;
                float v = acc[r] + bv;
                v = v > 0.f ? v : 0.01f * v;
                if (MODE == 1)
                    outf[idx] = 0.25f * (x0[idx] + bf2f(z1b[idx]) + bf2f(z2b[idx]) + v);
                else
                    outb[idx] = f2bf(v);
            }
        }
    }
}

// ---------------- launch ----------------

extern "C" void kernel_launch(void* const* d_in, const int* in_sizes, int n_in,
                              void* d_out, int out_size, void* d_ws, size_t ws_size,
                              hipStream_t stream) {
    const float* x     = (const float*)d_in[0];
    const int*   eidx  = (const int*)d_in[1];
    const int*   etype = (const int*)d_in[2];
    const float* eattr = (const float*)d_in[3];
    const float* W1 = (const float*)d_in[4];
    const float* b1 = (const float*)d_in[5];
    const float* W2 = (const float*)d_in[6];
    const float* b2 = (const float*)d_in[7];
    const float* W3 = (const float*)d_in[8];
    const float* b3 = (const float*)d_in[9];

    const int E = in_sizes[2];
    const int N = in_sizes[0] / DIM;
    const int* row = eidx;
    const int* col = eidx + E;

    char* w = (char*)d_ws;
    size_t off = 0;
    auto alloc = [&](size_t bytes) { size_t o = off; off = (off + bytes + 255) & ~255ULL; return o; };
    size_t deg_off = alloc((size_t)N * 4);
    int*   deg  = (int*)(w + deg_off);
    int*   fill = (int*)(w + alloc((size_t)N * 4));
    size_t zero_bytes = off - deg_off;
    u64*   ep   = (u64*)(w + alloc((size_t)N * SLOTS * 8));
    u16*   xb   = (u16*)(w + alloc((size_t)N * DIM * 2));
    u16*   z1b  = (u16*)(w + alloc((size_t)N * DIM * 2));
    u16*   z2b  = (u16*)(w + alloc((size_t)N * DIM * 2));
    u16*   Wt1  = (u16*)(w + alloc(65536 * 2));
    u16*   Wt2  = (u16*)(w + alloc(65536 * 2));
    u16*   Wt3  = (u16*)(w + alloc(65536 * 2));

    hipMemsetAsync(deg, 0, zero_bytes, stream);

    int nx4 = N * DIM / 4;
    int nEb = (E + 1023) / 1024;    // 4 edges per thread
    int nXb = (nx4 + 255) / 256;

    k_setup<<<nEb + nXb + 768, 256, 0, stream>>>(row, col, etype, eattr, E, deg, fill, ep,
                                                 x, xb, nx4, W1, W2, W3, Wt1, Wt2, Wt3, nEb, nXb);
    k_norm<<<(N + 3) / 4, 256, 0, stream>>>(fill, deg, ep, N);

    int grid = (N + 15) / 16;
    k_layer<0><<<grid, 1024, 0, stream>>>(xb,  fill, ep, Wt1, b1, nullptr, nullptr, nullptr, nullptr, z1b, N);
    k_layer<0><<<grid, 1024, 0, stream>>>(z1b, fill, ep, Wt2, b2, nullptr, nullptr, nullptr, nullptr, z2b, N);
    k_layer<1><<<grid, 1024, 0, stream>>>(z2b, fill, ep, Wt3, b3, x, z1b, z2b, (float*)d_out, nullptr, N);
}